// Round 6
// baseline (81.986 us; speedup 1.0000x reference)
//
#include <hip/hip_runtime.h>
#include <math.h>

#define DD  64
#define RPW 4    // independent rows (iteration chains) per wave
#define WPB 4    // waves per 256-thread block -> 16 rows/block

// tanh(a) = (e-1)/(e+1), e = exp2(a*2*log2(e)); v_exp_f32 + v_rcp_f32.
// |zl| <= ~13 << 44 (f32 exp2 overflow), so no clamp needed.
__device__ __forceinline__ float fast_tanh(float a) {
    const float e = __builtin_amdgcn_exp2f(a * 2.885390081777927f);
    return (e - 1.0f) * __builtin_amdgcn_rcpf(e + 1.0f);
}

// zl = xi + dot(w, zs); 4 independent FMA chains.
__device__ __forceinline__ float matvec_row(const float* __restrict__ w,
                                            const float* zs, float xi) {
    float a0 = xi, a1 = 0.f, a2 = 0.f, a3 = 0.f;
#pragma unroll
    for (int j = 0; j < DD; j += 16) {
        const float4 z0 = *reinterpret_cast<const float4*>(&zs[j]);
        const float4 z1 = *reinterpret_cast<const float4*>(&zs[j + 4]);
        const float4 z2 = *reinterpret_cast<const float4*>(&zs[j + 8]);
        const float4 z3 = *reinterpret_cast<const float4*>(&zs[j + 12]);
        a0 = fmaf(w[j],      z0.x, a0); a0 = fmaf(w[j + 1],  z0.y, a0);
        a0 = fmaf(w[j + 2],  z0.z, a0); a0 = fmaf(w[j + 3],  z0.w, a0);
        a1 = fmaf(w[j + 4],  z1.x, a1); a1 = fmaf(w[j + 5],  z1.y, a1);
        a1 = fmaf(w[j + 6],  z1.z, a1); a1 = fmaf(w[j + 7],  z1.w, a1);
        a2 = fmaf(w[j + 8],  z2.x, a2); a2 = fmaf(w[j + 9],  z2.y, a2);
        a2 = fmaf(w[j + 10], z2.z, a2); a2 = fmaf(w[j + 11], z2.w, a2);
        a3 = fmaf(w[j + 12], z3.x, a3); a3 = fmaf(w[j + 13], z3.y, a3);
        a3 = fmaf(w[j + 14], z3.z, a3); a3 = fmaf(w[j + 15], z3.w, a3);
    }
    return (a0 + a1) + (a2 + a3);
}

// One wave runs FOUR independent batch rows (iteration chains). Lane i owns
// element i of each row; W row i in registers is SHARED by all four chains
// (same lane -> same W row), so the extra cost is only ~16 accumulator VGPRs.
// While chain r stalls on its LDS broadcast round-trip / tanh latency, the
// other chains issue -> hides the ~45% stall fraction that made r1==r2==r4.
// Single-wave lockstep: wave_barrier is a compiler ordering fence only.
__global__ __launch_bounds__(64 * WPB)
void tanh_fixed_point(const float* __restrict__ x,
                      const float* __restrict__ W,
                      float* __restrict__ out)
{
    __shared__ float zsh[WPB][RPW][DD];
    const int lane = threadIdx.x & 63;
    const int wid  = threadIdx.x >> 6;
    const int b0   = (blockIdx.x * WPB + wid) * RPW;   // first of 4 rows
    float (*zs)[DD] = zsh[wid];

    float w[DD];
#pragma unroll
    for (int j = 0; j < DD; j += 4) {
        const float4 v = *reinterpret_cast<const float4*>(W + lane * DD + j);
        w[j] = v.x; w[j + 1] = v.y; w[j + 2] = v.z; w[j + 3] = v.w;
    }

    float xi[RPW], z[RPW];
#pragma unroll
    for (int r = 0; r < RPW; ++r) {
        xi[r] = x[(b0 + r) * DD + lane];
        z[r]  = fast_tanh(xi[r]);       // z0 = tanh(x), as reference
    }

    for (int it = 0; it < 64; ++it) {
#pragma unroll
        for (int r = 0; r < RPW; ++r) zs[r][lane] = z[r];
        __builtin_amdgcn_wave_barrier();
        float zn[RPW];
#pragma unroll
        for (int r = 0; r < RPW; ++r)   // 4 independent chains interleave
            zn[r] = fast_tanh(matvec_row(w, zs[r], xi[r]));
        __builtin_amdgcn_wave_barrier();
        bool conv = true;
#pragma unroll
        for (int r = 0; r < RPW; ++r) {
            conv = conv && (fabsf(zn[r] - z[r]) < 2.5e-6f);
            z[r] = zn[r];
        }
        if (__all(conv)) break;         // wave-uniform, ~3 instrs
    }

    // Mirror reference: zero rows with ||z - tanh(zW^T+x)||_2 > 1e-4.
#pragma unroll
    for (int r = 0; r < RPW; ++r) zs[r][lane] = z[r];
    __builtin_amdgcn_wave_barrier();
#pragma unroll
    for (int r = 0; r < RPW; ++r) {
        const float g = z[r] - fast_tanh(matvec_row(w, zs[r], xi[r]));
        float s = g * g;
#pragma unroll
        for (int off = 32; off; off >>= 1)
            s += __shfl_xor(s, off);
        if (s > 1e-8f) z[r] = 0.0f;
        out[(b0 + r) * DD + lane] = z[r];
    }
}

extern "C" void kernel_launch(void* const* d_in, const int* in_sizes, int n_in,
                              void* d_out, int out_size, void* d_ws, size_t ws_size,
                              hipStream_t stream)
{
    const float* x = (const float*)d_in[0];   // [B, 64] fp32
    const float* W = (const float*)d_in[1];   // [64, 64] fp32
    float* out     = (float*)d_out;           // [B, 64] fp32
    const int B = in_sizes[0] / DD;           // 4096
    tanh_fixed_point<<<B / (WPB * RPW), 64 * WPB, 0, stream>>>(x, W, out);
}

// Round 7
// 72.826 us; speedup vs baseline: 1.1258x; 1.1258x over previous
//
#include <hip/hip_runtime.h>
#include <math.h>

#define DD  64
#define WPB 4    // waves per 256-thread block, one batch row per wave

// tanh(a) = (e-1)/(e+1), e = exp2(a*2*log2(e)); v_exp_f32 + v_rcp_f32.
// |zl| <= ~13 << 44 (f32 exp2 overflow), so no clamp needed.
__device__ __forceinline__ float fast_tanh(float a) {
    const float e = __builtin_amdgcn_exp2f(a * 2.885390081777927f);
    return (e - 1.0f) * __builtin_amdgcn_rcpf(e + 1.0f);
}

// Broadcast z_j to all lanes WITHOUT the LDS pipe: v_readlane_b32 -> SGPR,
// then v_fmac with SGPR operand. The previous LDS version was CU-level LDS
// return-BW bound: 16 ds_read_b128/wave/iter x 64 lanes x 16B = 16KB/wave/iter
// over the CU-shared 128B/cyc pipe = ~2000 cyc/CU/iter with 16 waves/CU --
// the invariant ~26us across r1/r2/r4/r5. readlane+fmac moves the broadcast
// onto the per-SIMD VALU (4x wider in aggregate).
__device__ __forceinline__ float rl(float v, int lane) {
    return __int_as_float(__builtin_amdgcn_readlane(__float_as_int(v), lane));
}

// zl = xi + sum_j w[j] * z_j; 4 independent FMA chains, readlanes all
// independent (single source VGPR, distinct SGPR dsts -> full ILP).
__device__ __forceinline__ float matvec_rl(const float* __restrict__ w,
                                           float zv, float xi) {
    float a0 = xi, a1 = 0.f, a2 = 0.f, a3 = 0.f;
#pragma unroll
    for (int j = 0; j < DD; j += 4) {
        const float z0 = rl(zv, j);
        const float z1 = rl(zv, j + 1);
        const float z2 = rl(zv, j + 2);
        const float z3 = rl(zv, j + 3);
        a0 = fmaf(w[j],     z0, a0);
        a1 = fmaf(w[j + 1], z1, a1);
        a2 = fmaf(w[j + 2], z2, a2);
        a3 = fmaf(w[j + 3], z3, a3);
    }
    return (a0 + a1) + (a2 + a3);
}

// One wave per batch row; lane i owns element i and W row i in registers.
// No LDS at all. Tol 2.5e-6 (above eval-noise floor), cap 64 (rho<=0.6:
// unreachable), per-iteration __all() exit (v_cmp + s_cmp, ~free).
__global__ __launch_bounds__(64 * WPB)
void tanh_fixed_point(const float* __restrict__ x,
                      const float* __restrict__ W,
                      float* __restrict__ out)
{
    const int lane = threadIdx.x & 63;
    const int wid  = threadIdx.x >> 6;
    const int b    = blockIdx.x * WPB + wid;

    float w[DD];
#pragma unroll
    for (int j = 0; j < DD; j += 4) {
        const float4 v = *reinterpret_cast<const float4*>(W + lane * DD + j);
        w[j] = v.x; w[j + 1] = v.y; w[j + 2] = v.z; w[j + 3] = v.w;
    }

    const float xi = x[b * DD + lane];
    float z = fast_tanh(xi);            // z0 = tanh(x), as reference

    for (int it = 0; it < 64; ++it) {
        const float zn = fast_tanh(matvec_rl(w, z, xi));
        const bool conv = fabsf(zn - z) < 2.5e-6f;
        z = zn;
        if (__all(conv)) break;         // wave-uniform
    }

    // Mirror reference: zero rows with ||z - tanh(zW^T+x)||_2 > 1e-4.
    const float g = z - fast_tanh(matvec_rl(w, z, xi));
    float s = g * g;
#pragma unroll
    for (int off = 32; off; off >>= 1)
        s += __shfl_xor(s, off);
    if (s > 1e-8f) z = 0.0f;

    out[b * DD + lane] = z;
}

extern "C" void kernel_launch(void* const* d_in, const int* in_sizes, int n_in,
                              void* d_out, int out_size, void* d_ws, size_t ws_size,
                              hipStream_t stream)
{
    const float* x = (const float*)d_in[0];   // [B, 64] fp32
    const float* W = (const float*)d_in[1];   // [64, 64] fp32
    float* out     = (float*)d_out;           // [B, 64] fp32
    const int B = in_sizes[0] / DD;           // 4096
    tanh_fixed_point<<<B / WPB, 64 * WPB, 0, stream>>>(x, W, out);
}

// Round 8
// 72.674 us; speedup vs baseline: 1.1281x; 1.0021x over previous
//
#include <hip/hip_runtime.h>
#include <math.h>

#define DD   64
#define WPB  4    // waves per 256-thread block, one batch row per wave
#define NLDS 32   // z elements broadcast via LDS; the rest via readlane

// tanh(a) = 1 - 2/(e+1), e = exp2(a*2*log2(e)); v_exp_f32 + v_rcp_f32 + fma.
// |zl| <= ~13 << 44 (f32 exp2 overflow), so no clamp needed.
__device__ __forceinline__ float fast_tanh(float a) {
    const float e = __builtin_amdgcn_exp2f(a * 2.885390081777927f);
    return fmaf(-2.0f, __builtin_amdgcn_rcpf(e + 1.0f), 1.0f);
}

__device__ __forceinline__ float rl(float v, int lane) {
    return __int_as_float(__builtin_amdgcn_readlane(__float_as_int(v), lane));
}

// zl = xi + dot(w, z) with the z-broadcast SPLIT across two independent pipes:
//   z_0..31  via 8 same-address ds_read_b128 (LDS pipe, conflict-free bcast)
//   z_32..63 via 32 v_readlane (VALU/SALU path)
// r4 (all-LDS) and r7 (all-readlane) both sat at ~24-26us because each put
// the full broadcast on ONE pipe (~2000 cyc/CU/iter either way). Splitting
// runs the pipes concurrently -> ~1.7x lower per-iteration occupancy.
__device__ __forceinline__ float matvec_hybrid(const float* __restrict__ w,
                                               const float* zs, float zv,
                                               float xi) {
    float a0 = xi, a1 = 0.f, a2 = 0.f, a3 = 0.f;
#pragma unroll
    for (int j = 0; j < NLDS; j += 16) {
        const float4 z0 = *reinterpret_cast<const float4*>(&zs[j]);
        const float4 z1 = *reinterpret_cast<const float4*>(&zs[j + 4]);
        const float4 z2 = *reinterpret_cast<const float4*>(&zs[j + 8]);
        const float4 z3 = *reinterpret_cast<const float4*>(&zs[j + 12]);
        a0 = fmaf(w[j],      z0.x, a0); a0 = fmaf(w[j + 1],  z0.y, a0);
        a0 = fmaf(w[j + 2],  z0.z, a0); a0 = fmaf(w[j + 3],  z0.w, a0);
        a1 = fmaf(w[j + 4],  z1.x, a1); a1 = fmaf(w[j + 5],  z1.y, a1);
        a1 = fmaf(w[j + 6],  z1.z, a1); a1 = fmaf(w[j + 7],  z1.w, a1);
        a2 = fmaf(w[j + 8],  z2.x, a2); a2 = fmaf(w[j + 9],  z2.y, a2);
        a2 = fmaf(w[j + 10], z2.z, a2); a2 = fmaf(w[j + 11], z2.w, a2);
        a3 = fmaf(w[j + 12], z3.x, a3); a3 = fmaf(w[j + 13], z3.y, a3);
        a3 = fmaf(w[j + 14], z3.z, a3); a3 = fmaf(w[j + 15], z3.w, a3);
    }
#pragma unroll
    for (int j = NLDS; j < DD; j += 4) {
        a0 = fmaf(w[j],     rl(zv, j),     a0);
        a1 = fmaf(w[j + 1], rl(zv, j + 1), a1);
        a2 = fmaf(w[j + 2], rl(zv, j + 2), a2);
        a3 = fmaf(w[j + 3], rl(zv, j + 3), a3);
    }
    return (a0 + a1) + (a2 + a3);
}

// One wave per batch row; lane i owns element i and W row i in registers.
// Single-wave lockstep: wave_barrier is a compiler ordering fence only.
__global__ __launch_bounds__(64 * WPB)
void tanh_fixed_point(const float* __restrict__ x,
                      const float* __restrict__ W,
                      float* __restrict__ out)
{
    __shared__ float zsh[WPB][NLDS];
    const int lane = threadIdx.x & 63;
    const int wid  = threadIdx.x >> 6;
    const int b    = blockIdx.x * WPB + wid;
    float* zs = zsh[wid];

    float w[DD];
#pragma unroll
    for (int j = 0; j < DD; j += 4) {
        const float4 v = *reinterpret_cast<const float4*>(W + lane * DD + j);
        w[j] = v.x; w[j + 1] = v.y; w[j + 2] = v.z; w[j + 3] = v.w;
    }

    const float xi = x[b * DD + lane];
    float z = fast_tanh(xi);            // z0 = tanh(x), as reference

    for (int it = 0; it < 64; ++it) {
        if (lane < NLDS) zs[lane] = z;
        __builtin_amdgcn_wave_barrier();
        const float zn = fast_tanh(matvec_hybrid(w, zs, z, xi));
        __builtin_amdgcn_wave_barrier();
        const bool conv = fabsf(zn - z) < 2.5e-6f;
        z = zn;
        if (__all(conv)) break;         // wave-uniform
    }

    // Mirror reference: zero rows with ||z - tanh(zW^T+x)||_2 > 1e-4.
    if (lane < NLDS) zs[lane] = z;
    __builtin_amdgcn_wave_barrier();
    const float g = z - fast_tanh(matvec_hybrid(w, zs, z, xi));
    float s = g * g;
#pragma unroll
    for (int off = 32; off; off >>= 1)
        s += __shfl_xor(s, off);
    if (s > 1e-8f) z = 0.0f;

    out[b * DD + lane] = z;
}

extern "C" void kernel_launch(void* const* d_in, const int* in_sizes, int n_in,
                              void* d_out, int out_size, void* d_ws, size_t ws_size,
                              hipStream_t stream)
{
    const float* x = (const float*)d_in[0];   // [B, 64] fp32
    const float* W = (const float*)d_in[1];   // [64, 64] fp32
    float* out     = (float*)d_out;           // [B, 64] fp32
    const int B = in_sizes[0] / DD;           // 4096
    tanh_fixed_point<<<B / WPB, 64 * WPB, 0, stream>>>(x, W, out);
}

// Round 9
// 69.020 us; speedup vs baseline: 1.1879x; 1.0530x over previous
//
#include <hip/hip_runtime.h>
#include <math.h>

#define DD  64
#define WPB 4    // waves per 256-thread block, one batch row per wave

typedef float v2f __attribute__((ext_vector_type(2)));

// Packed fp32 FMA: d = a*b + c per 32-bit half. VOP3P, gfx908+; default
// op_sel gives lo*lo+lo / hi*hi+hi. Halves the dominant instruction count
// (64 v_fmac -> 32 v_pk_fma_f32). "v" on a 64-bit vector type allocates an
// even-aligned VGPR pair as the ISA requires.
__device__ __forceinline__ v2f pk_fma(v2f a, v2f b, v2f c) {
    v2f d;
    asm("v_pk_fma_f32 %0, %1, %2, %3" : "=v"(d) : "v"(a), "v"(b), "v"(c));
    return d;
}

// tanh(a) = 1 - 2/(e+1), e = exp2(a*2*log2(e)); 5 VALU instrs.
// |zl| <= ~13 << 44 (f32 exp2 overflow), so no clamp needed.
__device__ __forceinline__ float fast_tanh(float a) {
    const float e = __builtin_amdgcn_exp2f(a * 2.885390081777927f);
    return fmaf(-2.0f, __builtin_amdgcn_rcpf(e + 1.0f), 1.0f);
}

// zl = xi + dot(w, z): 16 ds_read_b128 (4 elems/instr, same-address bcast,
// conflict-free) + 32 v_pk_fma_f32. 8 independent scalar chains (4 accs x
// lo/hi). ~50 core instrs/iter vs ~130 in the readlane version: the r1-r8
// invariance traced to VALU issue count, not to which pipe broadcasts.
__device__ __forceinline__ float matvec_pk(const v2f* __restrict__ w2,
                                           const float* zs, float xi) {
    const float4* zs4 = reinterpret_cast<const float4*>(zs);
    v2f a0 = {xi, 0.0f}, a1 = {0.0f, 0.0f}, a2 = {0.0f, 0.0f}, a3 = {0.0f, 0.0f};
#pragma unroll
    for (int q = 0; q < 16; q += 2) {
        const float4 p = zs4[q];
        const float4 r = zs4[q + 1];
        a0 = pk_fma(w2[2 * q],     (v2f){p.x, p.y}, a0);
        a1 = pk_fma(w2[2 * q + 1], (v2f){p.z, p.w}, a1);
        a2 = pk_fma(w2[2 * q + 2], (v2f){r.x, r.y}, a2);
        a3 = pk_fma(w2[2 * q + 3], (v2f){r.z, r.w}, a3);
    }
    const v2f s = (a0 + a1) + (a2 + a3);
    return s.x + s.y;
}

// One wave per batch row; lane i owns element i and W row i (32 v2f regs).
// Single-wave lockstep: wave_barrier is a compiler ordering fence only.
// Tol 2.5e-6, cap 64, per-iteration __all() exit.
__global__ __launch_bounds__(64 * WPB)
void tanh_fixed_point(const float* __restrict__ x,
                      const float* __restrict__ W,
                      float* __restrict__ out)
{
    __shared__ alignas(16) float zsh[WPB][DD];
    const int lane = threadIdx.x & 63;
    const int wid  = threadIdx.x >> 6;
    const int b    = blockIdx.x * WPB + wid;
    float* zs = zsh[wid];

    v2f w2[DD / 2];
#pragma unroll
    for (int j = 0; j < DD; j += 4) {
        const float4 v = *reinterpret_cast<const float4*>(W + lane * DD + j);
        w2[j / 2]     = (v2f){v.x, v.y};
        w2[j / 2 + 1] = (v2f){v.z, v.w};
    }

    const float xi = x[b * DD + lane];
    float z = fast_tanh(xi);            // z0 = tanh(x), as reference

    for (int it = 0; it < 64; ++it) {
        zs[lane] = z;
        __builtin_amdgcn_wave_barrier();
        const float zn = fast_tanh(matvec_pk(w2, zs, xi));
        __builtin_amdgcn_wave_barrier();
        const bool conv = fabsf(zn - z) < 2.5e-6f;
        z = zn;
        if (__all(conv)) break;         // wave-uniform
    }

    // Mirror reference: zero rows with ||z - tanh(zW^T+x)||_2 > 1e-4.
    zs[lane] = z;
    __builtin_amdgcn_wave_barrier();
    const float g = z - fast_tanh(matvec_pk(w2, zs, xi));
    float s = g * g;
#pragma unroll
    for (int off = 32; off; off >>= 1)
        s += __shfl_xor(s, off);
    if (s > 1e-8f) z = 0.0f;

    out[b * DD + lane] = z;
}

extern "C" void kernel_launch(void* const* d_in, const int* in_sizes, int n_in,
                              void* d_out, int out_size, void* d_ws, size_t ws_size,
                              hipStream_t stream)
{
    const float* x = (const float*)d_in[0];   // [B, 64] fp32
    const float* W = (const float*)d_in[1];   // [64, 64] fp32
    float* out     = (float*)d_out;           // [B, 64] fp32
    const int B = in_sizes[0] / DD;           // 4096
    tanh_fixed_point<<<B / WPB, 64 * WPB, 0, stream>>>(x, W, out);
}